// Round 8
// baseline (365.812 us; speedup 1.0000x reference)
//
#include <hip/hip_runtime.h>

typedef float v2f __attribute__((ext_vector_type(2)));
typedef float v4f __attribute__((ext_vector_type(4)));
typedef _Float16 h4 __attribute__((ext_vector_type(4)));
typedef _Float16 h8 __attribute__((ext_vector_type(8)));
typedef _Float16 f16x8 __attribute__((ext_vector_type(8)));

template<int N> struct IC { static constexpr int value = N; };

// ---------------- CSR build ----------------

// zero deg + pack W hi/lo split transposed [col][k] + biases in one launch
__global__ void k_init(const float* __restrict__ w1_l, const float* __restrict__ w1_r,
                       const float* __restrict__ b1_l, const float* __restrict__ b1_r,
                       const float* __restrict__ w2_l, const float* __restrict__ w2_r,
                       const float* __restrict__ b2_l, const float* __restrict__ b2_r,
                       _Float16* __restrict__ wc1h, _Float16* __restrict__ wc1l,
                       _Float16* __restrict__ wc2h, _Float16* __restrict__ wc2l,
                       float* __restrict__ bc1, float* __restrict__ bc2,
                       int* __restrict__ deg, int n){
  int i = blockIdx.x*256 + threadIdx.x;
  if (i < n) deg[i] = 0;
  if (i < 256*128){                 // wc1t: [col 0..255][k 0..127], idx = col*128+k = i
    int col = i >> 7, k = i & 127;
    float v = (col < 128) ? w1_l[k*128 + col] : w1_r[k*128 + (col - 128)];
    _Float16 h = (_Float16)v;
    wc1h[i] = h; wc1l[i] = (_Float16)(v - (float)h);
  }
  if (i < 128*128){                 // wc2t: [col 0..127][k 0..127]
    int col = i >> 7, k = i & 127;
    float v = (col < 64) ? w2_l[k*64 + col] : w2_r[k*64 + (col - 64)];
    _Float16 h = (_Float16)v;
    wc2h[i] = h; wc2l[i] = (_Float16)(v - (float)h);
  }
  if (i < 256) bc1[i] = (i < 128) ? b1_l[i] : b1_r[i - 128];
  if (i < 128) bc2[i] = (i < 64)  ? b2_l[i] : b2_r[i - 64];
}

__global__ void k_hist(const int* __restrict__ dstp, int* __restrict__ deg, int E){
  int e = blockIdx.x*256 + threadIdx.x;
  if (e < E) atomicAdd(&deg[dstp[e]], 1);
}

__global__ void k_scan1(const int* __restrict__ deg, int* __restrict__ rowptr,
                        int* __restrict__ bsum, int n){
  __shared__ int s[256];
  int i = blockIdx.x*256 + threadIdx.x;
  int v = (i < n) ? deg[i] + 1 : 0;   // +1 = self loop
  s[threadIdx.x] = v;
  __syncthreads();
  for (int off = 1; off < 256; off <<= 1){
    int t = (threadIdx.x >= off) ? s[threadIdx.x - off] : 0;
    __syncthreads();
    s[threadIdx.x] += t;
    __syncthreads();
  }
  if (i < n) rowptr[i] = s[threadIdx.x] - v;   // exclusive within block
  if (threadIdx.x == 255) bsum[blockIdx.x] = s[255];
}

__global__ void k_scan2(int* bsum, int nb){
  __shared__ int s[256];
  int v = (threadIdx.x < nb) ? bsum[threadIdx.x] : 0;
  s[threadIdx.x] = v;
  __syncthreads();
  for (int off = 1; off < 256; off <<= 1){
    int t = (threadIdx.x >= off) ? s[threadIdx.x - off] : 0;
    __syncthreads();
    s[threadIdx.x] += t;
    __syncthreads();
  }
  if (threadIdx.x < nb) bsum[threadIdx.x] = s[threadIdx.x] - v;  // exclusive
}

// scan3 + scatter_init fused: finalize rowptr, seed self-loop + cursor
__global__ void k_scan3(int* rowptr, const int* __restrict__ bsum,
                        int* __restrict__ srcs, int* __restrict__ cursor,
                        int n, int total){
  int i = blockIdx.x*256 + threadIdx.x;
  if (i < n){
    int b = rowptr[i] + bsum[blockIdx.x];
    rowptr[i] = b;
    srcs[b] = i;          // self loop at segment head
    cursor[i] = b + 1;
  }
  if (i == 0) rowptr[n] = total;
}

// XCD-partitioned scatter (r7 known-good: 52 -> ~12 MB HBM write).
#define SCB 256   // chunks per region

__global__ __launch_bounds__(256) void k_scatter_xcd(
    const int* __restrict__ srcp, const int* __restrict__ dstp,
    int* __restrict__ cursor, int* __restrict__ srcs, int E, int n){
  int b = blockIdx.x;
  int reg = b & 7;
  int chunk = b >> 3;
  int lo = (int)((long long)reg * n >> 3);
  int hi = (int)((long long)(reg + 1) * n >> 3);
  int per = (E + SCB - 1) / SCB;
  int e0 = chunk * per;
  int e1 = min(E, e0 + per);
  for (int e = e0 + threadIdx.x; e < e1; e += 256){
    int d = dstp[e];
    if (d >= lo && d < hi){
      int p = atomicAdd(&cursor[d], 1);
      srcs[p] = srcp[e];
    }
  }
}

// ---------------- split-fp16 MFMA GEMM, 64x128 tile, BK=32 ----------------
// fp32 vector GEMM was LDS-throughput-bound. MFMA 16x16x32_f16 fragments are
// 8 contiguous K per lane; C: col=lane&15, row=(lane>>4)*4+i. Split precision:
// D = Ah·Wh + Ah·Wl + Al·Wh -> ~fp32 accuracy. W pre-split/transposed [col][k].

#define MBM 64
#define MBN 128
#define MBK 32

__device__ __forceinline__ int lds_idx(int row, int k){
  return row*32 + ((((k >> 3) ^ row) & 3) << 3) + (k & 7);
}

__global__ __launch_bounds__(256) void k_gemm_mfma(
    const float* __restrict__ A, const _Float16* __restrict__ Wh,
    const _Float16* __restrict__ Wl, const float* __restrict__ bias,
    _Float16* __restrict__ Cxl, float* __restrict__ Cxr,
    int M, int K, int N, int xlCols){
  __shared__ _Float16 Ah[MBM*MBK], Al[MBM*MBK];
  __shared__ _Float16 Bh[MBN*MBK], Bl[MBN*MBK];
  int bm = blockIdx.x * MBM, bn = blockIdx.y * MBN;
  int tid = threadIdx.x;
  int lane = tid & 63, wv = tid >> 6;
  v4f acc[8] = {};
  // per-lane fragment byte pattern: row/col low bits = lane&15, k-chunk = lane>>4
  const int fragoff = (lane & 15)*32 + ((((lane >> 4) ^ lane) & 3) << 3);
  for (int k0 = 0; k0 < K; k0 += MBK){
    // stage A: 64x32 fp32 -> hi/lo fp16 (512 float4 slots, 2/thread)
    #pragma unroll
    for (int l = 0; l < 2; l++){
      int idx = tid + l*256;
      int r = idx >> 3, kq = (idx & 7) * 4;
      float4 v = make_float4(0.f, 0.f, 0.f, 0.f);
      if (bm + r < M) v = *(const float4*)(A + (size_t)(bm + r)*K + k0 + kq);
      _Float16 e0 = (_Float16)v.x, e1 = (_Float16)v.y,
               e2 = (_Float16)v.z, e3 = (_Float16)v.w;
      h4 hh = {e0, e1, e2, e3};
      h4 ll = {(_Float16)(v.x - (float)e0), (_Float16)(v.y - (float)e1),
               (_Float16)(v.z - (float)e2), (_Float16)(v.w - (float)e3)};
      int o = lds_idx(r, kq);
      *(h4*)(&Ah[o]) = hh;
      *(h4*)(&Al[o]) = ll;
    }
    // stage B: 128x32 fp16 hi+lo from pre-split [col][k] global (512 16B slots)
    #pragma unroll
    for (int l = 0; l < 2; l++){
      int idx = tid + l*256;
      int c = idx >> 2, kc = (idx & 3) * 8;
      size_t go = (size_t)(bn + c)*K + k0 + kc;
      int o = lds_idx(c, kc);
      *(f16x8*)(&Bh[o]) = *(const f16x8*)(Wh + go);
      *(f16x8*)(&Bl[o]) = *(const f16x8*)(Wl + go);
    }
    __syncthreads();
    f16x8 ah = *(const f16x8*)(&Ah[wv*16*32 + fragoff]);
    f16x8 al = *(const f16x8*)(&Al[wv*16*32 + fragoff]);
    #pragma unroll
    for (int t = 0; t < 8; t++){
      f16x8 bh = *(const f16x8*)(&Bh[t*16*32 + fragoff]);
      f16x8 bl = *(const f16x8*)(&Bl[t*16*32 + fragoff]);
      acc[t] = __builtin_amdgcn_mfma_f32_16x16x32_f16(ah, bh, acc[t], 0, 0, 0);
      acc[t] = __builtin_amdgcn_mfma_f32_16x16x32_f16(ah, bl, acc[t], 0, 0, 0);
      acc[t] = __builtin_amdgcn_mfma_f32_16x16x32_f16(al, bh, acc[t], 0, 0, 0);
    }
    __syncthreads();
  }
  // epilogue: C[row][col], col = lane&15, row = (lane>>4)*4 + i
  int rbase = bm + wv*16 + (lane >> 4)*4;
  int cl = lane & 15;
  int NR = N - xlCols;
  #pragma unroll
  for (int t = 0; t < 8; t++){
    int col = bn + t*16 + cl;
    float bv = bias[col];
    bool isXl = (bn + t*16) < xlCols;   // block-uniform per tile
    #pragma unroll
    for (int i = 0; i < 4; i++){
      int r = rbase + i;
      if (r < M){
        float o = acc[t][i] + bv;
        if (isXl) Cxl[(size_t)r*xlCols + col] = (_Float16)o;
        else      Cxr[(size_t)r*NR + (col - xlCols)] = o;
      }
    }
  }
}

// ---------------- DPP adds (VALU pipe, no DS ops) ----------------

template<int CTRL>
__device__ __forceinline__ float dpp_add(float x){
  int t = __builtin_amdgcn_update_dpp(0, __float_as_int(x), CTRL, 0xf, 0xf, true);
  return x + __int_as_float(t);
}

// ---------------- fused GATv2 layer: 8-lane groups, h8 fp16 gather --------
// r8: restructure from 16-lane/h4 to 8-lane groups x 16B loads. Each group
// of 8 lanes owns one (edge, head): 4 edges/iter (H=2), 8 edges/iter (H=1)
// -- 2x the previous rate; the per-edge DPP/mask/loop overhead halves
// (~11.5 vs ~17.5 VALU/edge). Group reduce: in-lane 8-sum, DPP row_shr
// 1,2,4 (lane 8g+7 = group sum), ds_swizzle 0xF8 (and=0x18,or=0x07)
// broadcasts lane 7 of each 8-group. Loads: global_load_dwordx4.
// xlh layout: [n][H*64] fp16 head-major; xr: [n][H*64] fp32.

template<int H>
__global__ __launch_bounds__(256) void k_gat_fused(
    const _Float16* __restrict__ xlh, const float* __restrict__ xr,
    const int* __restrict__ rowptr, const int* __restrict__ srcs,
    const float* __restrict__ att, const float* __restrict__ bias,
    float* __restrict__ out, int n){
  int gid = blockIdx.x * blockDim.x + threadIdx.x;
  int nd = gid >> 6, lane = gid & 63;
  if (nd >= n) return;
  constexpr int SHIFTB = (H == 2) ? 8 : 7;      // bytes per fp16 xl row
  constexpr int EPI = (H == 2) ? 4 : 8;         // edges per iteration
  const int g8 = lane >> 3, q8 = lane & 7;
  const int hsel  = (H == 2) ? (g8 & 1) : 0;
  const int elane = (H == 2) ? (g8 >> 1) : g8;  // edge-in-iter
  const int fpos = hsel*64 + q8*8;              // f16 index of lane's 8 feats
  const unsigned foff = (unsigned)fpos * 2u;    // byte offset (16B aligned)
  const char* __restrict__ xbase = (const char*)xlh;
  v4f xr0 = *(const v4f*)(xr + (size_t)nd*(H*64) + fpos);
  v4f xr1 = *(const v4f*)(xr + (size_t)nd*(H*64) + fpos + 4);
  v4f av0 = *(const v4f*)(att + fpos);
  v4f av1 = *(const v4f*)(att + fpos + 4);
  v4f acc0 = {0.f,0.f,0.f,0.f}, acc1 = {0.f,0.f,0.f,0.f};
  float den = 0.f;
  int s0 = rowptr[nd], s1 = rowptr[nd+1];
  for (int base = s0; base < s1; base += 64){
    int idx = base + lane;
    int sv = (idx < s1) ? srcs[idx] : 0;   // pad lanes hold 0 (valid row)
    int cnt = min(64, s1 - base);
    // batched gather: U iterations, all loads issued before any compute
    auto batchU = [&](int i, auto Uc, bool full){
      constexpr int U = decltype(Uc)::value;
      int aidx[U];
      h8 hv[U];
      #pragma unroll
      for (int u = 0; u < U; u++)
        aidx[u] = __builtin_amdgcn_ds_bpermute((i + u*EPI + elane) << 2, sv);
      #pragma unroll
      for (int u = 0; u < U; u++)
        hv[u] = *(const h8*)(xbase + (((unsigned)aidx[u] << SHIFTB) + foff));
      #pragma unroll
      for (int u = 0; u < U; u++){
        v4f xv0 = {(float)hv[u][0], (float)hv[u][1], (float)hv[u][2], (float)hv[u][3]};
        v4f xv1 = {(float)hv[u][4], (float)hv[u][5], (float)hv[u][6], (float)hv[u][7]};
        v4f t0 = xv0 + xr0, t1 = xv1 + xr1;
        v4f l0 = __builtin_elementwise_max(t0, t0 * 0.2f);   // leaky_relu 0.2
        v4f l1 = __builtin_elementwise_max(t1, t1 * 0.2f);
        v4f pr = l0 * av0 + l1 * av1;
        float p = (pr.x + pr.y) + (pr.z + pr.w);
        p = dpp_add<0x111>(p);   // row_shr:1
        p = dpp_add<0x112>(p);   // row_shr:2
        p = dpp_add<0x114>(p);   // row_shr:4 -> lane 8g+7 = group sum
        p = __int_as_float(__builtin_amdgcn_ds_swizzle(__float_as_int(p), 0x00F8));
        float ex = __expf(p);    // scores bounded; softmax w/o max
        if (!full) ex = (elane < cnt - (i + u*EPI)) ? ex : 0.f;  // tail mask
        den += ex;
        acc0 += xv0 * ex;
        acc1 += xv1 * ex;
      }
    };
    int i = 0;
    for (; i + 8*EPI <= cnt; i += 8*EPI) batchU(i, IC<8>{}, true);
    if (i + 4*EPI <= cnt){ batchU(i, IC<4>{}, true); i += 4*EPI; }
    if (i + 2*EPI <= cnt){ batchU(i, IC<2>{}, true); i += 2*EPI; }
    for (; i < cnt; i += EPI) batchU(i, IC<1>{}, i + EPI <= cnt);
  }
  // combine groups that accumulated different edges (same output slot)
  auto comb = [&](int m){
    den    += __shfl_xor(den,    m, 64);
    acc0.x += __shfl_xor(acc0.x, m, 64);
    acc0.y += __shfl_xor(acc0.y, m, 64);
    acc0.z += __shfl_xor(acc0.z, m, 64);
    acc0.w += __shfl_xor(acc0.w, m, 64);
    acc1.x += __shfl_xor(acc1.x, m, 64);
    acc1.y += __shfl_xor(acc1.y, m, 64);
    acc1.z += __shfl_xor(acc1.z, m, 64);
    acc1.w += __shfl_xor(acc1.w, m, 64);
  };
  if (H == 1) comb(8);
  comb(16);
  comb(32);
  if (lane < 8*H){
    v4f b0 = *(const v4f*)(bias + fpos);
    v4f b1 = *(const v4f*)(bias + fpos + 4);
    float inv = 1.f / (den + 1e-16f);
    v4f o0 = acc0 * inv + b0;
    v4f o1 = acc1 * inv + b1;
    v4f z = {0.f,0.f,0.f,0.f};
    o0 = __builtin_elementwise_max(o0, z);
    o1 = __builtin_elementwise_max(o1, z);
    *(v4f*)(out + (size_t)nd*(H*64) + fpos) = o0;
    *(v4f*)(out + (size_t)nd*(H*64) + fpos + 4) = o1;
  }
}

// ---------------- gate: relu(h2@gw1+gb1)@gw2+gb2 -> exp, fused ------------

__global__ __launch_bounds__(256) void k_gate(
    const float* __restrict__ h2, const float* __restrict__ gw1,
    const float* __restrict__ gb1, const float* __restrict__ gw2,
    const float* __restrict__ gb2, float* __restrict__ exn, int M){
  __shared__ float As[32][64 + 4];
  __shared__ float Ws[32][64];
  int bm = blockIdx.x * 64;
  int tid = threadIdx.x;
  int tx = tid & 15, ty = tid >> 4;
  float acc[4][4] = {};
  for (int k0 = 0; k0 < 64; k0 += 32){
    #pragma unroll
    for (int l = 0; l < 2; l++){
      int idx = tid + l*256;
      int r = idx >> 3, c4 = (idx & 7) * 4;
      float4 v = make_float4(0.f, 0.f, 0.f, 0.f);
      if (bm + r < M) v = *(const float4*)(h2 + (size_t)(bm + r)*64 + k0 + c4);
      As[c4+0][r] = v.x; As[c4+1][r] = v.y; As[c4+2][r] = v.z; As[c4+3][r] = v.w;
      int kr = idx >> 4, wc4 = (idx & 15) * 4;
      *(float4*)(&Ws[kr][wc4]) = *(const float4*)(gw1 + (size_t)(k0 + kr)*64 + wc4);
    }
    __syncthreads();
    #pragma unroll
    for (int k = 0; k < 32; k++){
      float4 a4 = *(const float4*)(&As[k][ty*4]);
      float4 w4 = *(const float4*)(&Ws[k][tx*4]);
      float av[4] = {a4.x, a4.y, a4.z, a4.w};
      float wv[4] = {w4.x, w4.y, w4.z, w4.w};
      #pragma unroll
      for (int i = 0; i < 4; i++)
        #pragma unroll
        for (int j = 0; j < 4; j++)
          acc[i][j] = fmaf(av[i], wv[j], acc[i][j]);
    }
    __syncthreads();
  }
  float4 b4 = *(const float4*)(gb1 + tx*4);
  float4 w2 = *(const float4*)(gw2 + tx*4);
  float gb2v = gb2[0];
  #pragma unroll
  for (int i = 0; i < 4; i++){
    float p = fmaxf(acc[i][0] + b4.x, 0.f) * w2.x;
    p = fmaf(fmaxf(acc[i][1] + b4.y, 0.f), w2.y, p);
    p = fmaf(fmaxf(acc[i][2] + b4.z, 0.f), w2.z, p);
    p = fmaf(fmaxf(acc[i][3] + b4.w, 0.f), w2.w, p);
    p = dpp_add<0x111>(p);
    p = dpp_add<0x112>(p);
    p = dpp_add<0x114>(p);
    p = dpp_add<0x118>(p);     // lane tx==15 holds the 16-lane row sum
    if (tx == 15){
      int r = bm + ty*4 + i;
      if (r < M) exn[r] = __expf(p + gb2v);
    }
  }
}

// ---------------- pool + MLP head: one block per batch segment ----------------

__global__ __launch_bounds__(1024) void k_pool_mlp(
    const float* __restrict__ h2, const float* __restrict__ exn,
    const int* __restrict__ batch, int n,
    const float* __restrict__ l1w, const float* __restrict__ l1b,
    const float* __restrict__ l2w, const float* __restrict__ l2b,
    float* __restrict__ out){
  __shared__ float accs[16][64];
  __shared__ float dens[16];
  int b = blockIdx.x;
  int tid = threadIdx.x, lane = tid & 63, wv = tid >> 6;
  int lo = 0, hi = n;
  while (lo < hi){ int m = (lo + hi) >> 1; if (batch[m] < b) lo = m + 1; else hi = m; }
  int start = lo;
  hi = n;
  while (lo < hi){ int m = (lo + hi) >> 1; if (batch[m] < b + 1) lo = m + 1; else hi = m; }
  int end = lo;
  float acc = 0.f, den = 0.f;
  for (int nd = start + wv; nd < end; nd += 16){
    float ex = exn[nd];
    den += ex;
    acc = fmaf(ex, h2[(size_t)nd*64 + lane], acc);
  }
  accs[wv][lane] = acc;
  if (lane == 0) dens[wv] = den;
  __syncthreads();
  if (wv == 0){
    float p = 0.f, d = 0.f;
    #pragma unroll
    for (int w = 0; w < 16; w++){ p += accs[w][lane]; d += dens[w]; }
    p = p / (d + 1e-16f);
    float t = l1b[lane];
    #pragma unroll
    for (int k = 0; k < 64; k++)
      t = fmaf(__shfl(p, k, 64), l1w[k*64 + lane], t);
    t = fmaxf(t, 0.f) * l2w[lane];
    #pragma unroll
    for (int off = 32; off; off >>= 1) t += __shfl_xor(t, off, 64);
    if (lane == 0) out[b] = t + l2b[0];
  }
}

// ---------------- launch (12 dispatches) ----------------

extern "C" void kernel_launch(void* const* d_in, const int* in_sizes, int n_in,
                              void* d_out, int out_size, void* d_ws, size_t ws_size,
                              hipStream_t stream){
  const float* x    = (const float*)d_in[0];
  const int*   ei   = (const int*)  d_in[1];
  const int*   batch= (const int*)  d_in[2];
  const float* w1_l = (const float*)d_in[3];  const float* b1_l = (const float*)d_in[4];
  const float* w1_r = (const float*)d_in[5];  const float* b1_r = (const float*)d_in[6];
  const float* att1 = (const float*)d_in[7];  const float* bias1= (const float*)d_in[8];
  const float* w2_l = (const float*)d_in[9];  const float* b2_l = (const float*)d_in[10];
  const float* w2_r = (const float*)d_in[11]; const float* b2_r = (const float*)d_in[12];
  const float* att2 = (const float*)d_in[13]; const float* bias2= (const float*)d_in[14];
  const float* gw1  = (const float*)d_in[15]; const float* gb1  = (const float*)d_in[16];
  const float* gw2  = (const float*)d_in[17]; const float* gb2  = (const float*)d_in[18];
  const float* l1w  = (const float*)d_in[19]; const float* l1b  = (const float*)d_in[20];
  const float* l2w  = (const float*)d_in[21]; const float* l2b  = (const float*)d_in[22];

  const int n = in_sizes[0] / 128;
  const int E = in_sizes[1] / 2;
  const int Bb = out_size;
  const int Etot = E + n;
  const int* srcp = ei;
  const int* dstp = ei + E;

  char* wsbase = (char*)d_ws;
  size_t off = 0;
  auto alloc = [&](size_t bytes)->char*{
    char* p = wsbase + off;
    off = (off + bytes + 255) & ~(size_t)255;
    return p;
  };
  int*   deg    = (int*)  alloc((size_t)n*4);
  int*   rowptr = (int*)  alloc((size_t)(n+1)*4);
  int*   cursor = (int*)  alloc((size_t)n*4);
  int*   bsum   = (int*)  alloc(1024);
  int*   srcs   = (int*)  alloc((size_t)Etot*4);
  _Float16* wc1h = (_Float16*)alloc(256*128*2);
  _Float16* wc1l = (_Float16*)alloc(256*128*2);
  _Float16* wc2h = (_Float16*)alloc(128*128*2);
  _Float16* wc2l = (_Float16*)alloc(128*128*2);
  float* bc1    = (float*)alloc(256*4);
  float* bc2    = (float*)alloc(128*4);
  // region A: xlh1 [n][128] fp16; reused as xlh2 [n][64] fp16
  _Float16* xlh1 = (_Float16*)alloc((size_t)n*128*2);
  // region B: xr1 [n][128] fp32; reused as xr2 [n][64] + h2 [n][64]
  float* xr1    = (float*)alloc((size_t)n*128*4);
  // region C: h1 [n][128] fp32; reused as exn [n]
  float* h1     = (float*)alloc((size_t)n*128*4);
  _Float16* xlh2 = xlh1;
  float* xr2 = xr1;
  float* h2  = xr1 + (size_t)n*64;
  float* exn = h1;

  int nb = (n + 255) / 256;
  int eb = (E + 255) / 256;
  int ib = (((n > 32768) ? n : 32768) + 255) / 256;

  // CSR build + weight packing
  k_init<<<ib, 256, 0, stream>>>(w1_l, w1_r, b1_l, b1_r, w2_l, w2_r, b2_l, b2_r,
                                 wc1h, wc1l, wc2h, wc2l, bc1, bc2, deg, n);
  k_hist<<<eb, 256, 0, stream>>>(dstp, deg, E);
  k_scan1<<<nb, 256, 0, stream>>>(deg, rowptr, bsum, n);
  k_scan2<<<1, 256, 0, stream>>>(bsum, nb);
  k_scan3<<<nb, 256, 0, stream>>>(rowptr, bsum, srcs, cursor, n, Etot);
  k_scatter_xcd<<<8*SCB, 256, 0, stream>>>(srcp, dstp, cursor, srcs, E, n);

  // layer 1: mfma gemm -> xlh1 (fp16, cols 0..127) + xr1 (fp32, cols 128..255)
  dim3 g1((n + MBM - 1)/MBM, 2);
  k_gemm_mfma<<<g1, 256, 0, stream>>>(x, wc1h, wc1l, bc1, xlh1, xr1, n, 128, 256, 128);
  long long thr = (long long)n * 64;           // one wave per node
  int gatb = (int)((thr + 255)/256);
  k_gat_fused<2><<<gatb, 256, 0, stream>>>(xlh1, xr1, rowptr, srcs, att1, bias1, h1, n);

  // layer 2: mfma gemm -> xlh2 (fp16, cols 0..63) + xr2 (fp32, cols 64..127)
  dim3 g2((n + MBM - 1)/MBM, 1);
  k_gemm_mfma<<<g2, 256, 0, stream>>>(h1, wc2h, wc2l, bc2, xlh2, xr2, n, 128, 128, 64);
  k_gat_fused<1><<<gatb, 256, 0, stream>>>(xlh2, xr2, rowptr, srcs, att2, bias2, h2, n);

  // gate (gemm + gw2-dot + exp fused)
  k_gate<<<(n + 63)/64, 256, 0, stream>>>(h2, gw1, gb1, gw2, gb2, exn, n);

  // pool + MLP head
  k_pool_mlp<<<Bb, 1024, 0, stream>>>(h2, exn, batch, n, l1w, l1b, l2w, l2b, (float*)d_out);
}

// Round 10
// 336.701 us; speedup vs baseline: 1.0865x; 1.0865x over previous
//
#include <hip/hip_runtime.h>

typedef float v2f __attribute__((ext_vector_type(2)));
typedef float v4f __attribute__((ext_vector_type(4)));
typedef _Float16 h4 __attribute__((ext_vector_type(4)));
typedef _Float16 f16x8 __attribute__((ext_vector_type(8)));

template<int N> struct IC { static constexpr int value = N; };

// ---------------- CSR build ----------------

// zero deg + pack W hi/lo split transposed [col][k] + biases in one launch
__global__ void k_init(const float* __restrict__ w1_l, const float* __restrict__ w1_r,
                       const float* __restrict__ b1_l, const float* __restrict__ b1_r,
                       const float* __restrict__ w2_l, const float* __restrict__ w2_r,
                       const float* __restrict__ b2_l, const float* __restrict__ b2_r,
                       _Float16* __restrict__ wc1h, _Float16* __restrict__ wc1l,
                       _Float16* __restrict__ wc2h, _Float16* __restrict__ wc2l,
                       float* __restrict__ bc1, float* __restrict__ bc2,
                       int* __restrict__ deg, int n){
  int i = blockIdx.x*256 + threadIdx.x;
  if (i < n) deg[i] = 0;
  if (i < 256*128){                 // wc1t: [col 0..255][k 0..127], idx = col*128+k = i
    int col = i >> 7, k = i & 127;
    float v = (col < 128) ? w1_l[k*128 + col] : w1_r[k*128 + (col - 128)];
    _Float16 h = (_Float16)v;
    wc1h[i] = h; wc1l[i] = (_Float16)(v - (float)h);
  }
  if (i < 128*128){                 // wc2t: [col 0..127][k 0..127]
    int col = i >> 7, k = i & 127;
    float v = (col < 64) ? w2_l[k*64 + col] : w2_r[k*64 + (col - 64)];
    _Float16 h = (_Float16)v;
    wc2h[i] = h; wc2l[i] = (_Float16)(v - (float)h);
  }
  if (i < 256) bc1[i] = (i < 128) ? b1_l[i] : b1_r[i - 128];
  if (i < 128) bc2[i] = (i < 64)  ? b2_l[i] : b2_r[i - 64];
}

// r9: XCD-partitioned histogram (same mechanism as r7's scatter fix: deg
// atomic lines were bouncing across 8 non-coherent XCD L2s). Block b =
// (chunk b>>3, region b&7); each region's 25KB deg slice stays in one L2.
#define SCB 256   // chunks per region

__global__ __launch_bounds__(256) void k_hist_xcd(
    const int* __restrict__ dstp, int* __restrict__ deg, int E, int n){
  int b = blockIdx.x;
  int reg = b & 7;
  int chunk = b >> 3;
  int lo = (int)((long long)reg * n >> 3);
  int hi = (int)((long long)(reg + 1) * n >> 3);
  int per = (E + SCB - 1) / SCB;
  int e0 = chunk * per;
  int e1 = min(E, e0 + per);
  for (int e = e0 + threadIdx.x; e < e1; e += 256){
    int d = dstp[e];
    if (d >= lo && d < hi) atomicAdd(&deg[d], 1);
  }
}

__global__ void k_scan1(const int* __restrict__ deg, int* __restrict__ rowptr,
                        int* __restrict__ bsum, int n){
  __shared__ int s[256];
  int i = blockIdx.x*256 + threadIdx.x;
  int v = (i < n) ? deg[i] + 1 : 0;   // +1 = self loop
  s[threadIdx.x] = v;
  __syncthreads();
  for (int off = 1; off < 256; off <<= 1){
    int t = (threadIdx.x >= off) ? s[threadIdx.x - off] : 0;
    __syncthreads();
    s[threadIdx.x] += t;
    __syncthreads();
  }
  if (i < n) rowptr[i] = s[threadIdx.x] - v;   // exclusive within block
  if (threadIdx.x == 255) bsum[blockIdx.x] = s[255];
}

__global__ void k_scan2(int* bsum, int nb){
  __shared__ int s[256];
  int v = (threadIdx.x < nb) ? bsum[threadIdx.x] : 0;
  s[threadIdx.x] = v;
  __syncthreads();
  for (int off = 1; off < 256; off <<= 1){
    int t = (threadIdx.x >= off) ? s[threadIdx.x - off] : 0;
    __syncthreads();
    s[threadIdx.x] += t;
    __syncthreads();
  }
  if (threadIdx.x < nb) bsum[threadIdx.x] = s[threadIdx.x] - v;  // exclusive
}

// scan3 + scatter_init fused: finalize rowptr, seed self-loop + cursor
__global__ void k_scan3(int* rowptr, const int* __restrict__ bsum,
                        int* __restrict__ srcs, int* __restrict__ cursor,
                        int n, int total){
  int i = blockIdx.x*256 + threadIdx.x;
  if (i < n){
    int b = rowptr[i] + bsum[blockIdx.x];
    rowptr[i] = b;
    srcs[b] = i;          // self loop at segment head
    cursor[i] = b + 1;
  }
  if (i == 0) rowptr[n] = total;
}

// XCD-partitioned scatter (r7 known-good: 52 -> ~12 MB HBM write).
__global__ __launch_bounds__(256) void k_scatter_xcd(
    const int* __restrict__ srcp, const int* __restrict__ dstp,
    int* __restrict__ cursor, int* __restrict__ srcs, int E, int n){
  int b = blockIdx.x;
  int reg = b & 7;
  int chunk = b >> 3;
  int lo = (int)((long long)reg * n >> 3);
  int hi = (int)((long long)(reg + 1) * n >> 3);
  int per = (E + SCB - 1) / SCB;
  int e0 = chunk * per;
  int e1 = min(E, e0 + per);
  for (int e = e0 + threadIdx.x; e < e1; e += 256){
    int d = dstp[e];
    if (d >= lo && d < hi){
      int p = atomicAdd(&cursor[d], 1);
      srcs[p] = srcp[e];
    }
  }
}

// ---------------- split-fp16 MFMA GEMM, 64x128 tile, BK=32 ----------------
// fp32 vector GEMM was LDS-throughput-bound. MFMA 16x16x32_f16 fragments are
// 8 contiguous K per lane; C: col=lane&15, row=(lane>>4)*4+i. Split precision:
// D = Ah·Wh + Ah·Wl + Al·Wh -> ~fp32 accuracy. W pre-split/transposed [col][k].

#define MBM 64
#define MBN 128
#define MBK 32

__device__ __forceinline__ int lds_idx(int row, int k){
  return row*32 + ((((k >> 3) ^ row) & 3) << 3) + (k & 7);
}

__global__ __launch_bounds__(256) void k_gemm_mfma(
    const float* __restrict__ A, const _Float16* __restrict__ Wh,
    const _Float16* __restrict__ Wl, const float* __restrict__ bias,
    _Float16* __restrict__ Cxl, float* __restrict__ Cxr,
    int M, int K, int N, int xlCols){
  __shared__ _Float16 Ah[MBM*MBK], Al[MBM*MBK];
  __shared__ _Float16 Bh[MBN*MBK], Bl[MBN*MBK];
  int bm = blockIdx.x * MBM, bn = blockIdx.y * MBN;
  int tid = threadIdx.x;
  int lane = tid & 63, wv = tid >> 6;
  v4f acc[8] = {};
  // per-lane fragment byte pattern: row/col low bits = lane&15, k-chunk = lane>>4
  const int fragoff = (lane & 15)*32 + ((((lane >> 4) ^ lane) & 3) << 3);
  for (int k0 = 0; k0 < K; k0 += MBK){
    // stage A: 64x32 fp32 -> hi/lo fp16 (512 float4 slots, 2/thread)
    #pragma unroll
    for (int l = 0; l < 2; l++){
      int idx = tid + l*256;
      int r = idx >> 3, kq = (idx & 7) * 4;
      float4 v = make_float4(0.f, 0.f, 0.f, 0.f);
      if (bm + r < M) v = *(const float4*)(A + (size_t)(bm + r)*K + k0 + kq);
      _Float16 e0 = (_Float16)v.x, e1 = (_Float16)v.y,
               e2 = (_Float16)v.z, e3 = (_Float16)v.w;
      h4 hh = {e0, e1, e2, e3};
      h4 ll = {(_Float16)(v.x - (float)e0), (_Float16)(v.y - (float)e1),
               (_Float16)(v.z - (float)e2), (_Float16)(v.w - (float)e3)};
      int o = lds_idx(r, kq);
      *(h4*)(&Ah[o]) = hh;
      *(h4*)(&Al[o]) = ll;
    }
    // stage B: 128x32 fp16 hi+lo from pre-split [col][k] global (512 16B slots)
    #pragma unroll
    for (int l = 0; l < 2; l++){
      int idx = tid + l*256;
      int c = idx >> 2, kc = (idx & 3) * 8;
      size_t go = (size_t)(bn + c)*K + k0 + kc;
      int o = lds_idx(c, kc);
      *(f16x8*)(&Bh[o]) = *(const f16x8*)(Wh + go);
      *(f16x8*)(&Bl[o]) = *(const f16x8*)(Wl + go);
    }
    __syncthreads();
    f16x8 ah = *(const f16x8*)(&Ah[wv*16*32 + fragoff]);
    f16x8 al = *(const f16x8*)(&Al[wv*16*32 + fragoff]);
    #pragma unroll
    for (int t = 0; t < 8; t++){
      f16x8 bh = *(const f16x8*)(&Bh[t*16*32 + fragoff]);
      f16x8 bl = *(const f16x8*)(&Bl[t*16*32 + fragoff]);
      acc[t] = __builtin_amdgcn_mfma_f32_16x16x32_f16(ah, bh, acc[t], 0, 0, 0);
      acc[t] = __builtin_amdgcn_mfma_f32_16x16x32_f16(ah, bl, acc[t], 0, 0, 0);
      acc[t] = __builtin_amdgcn_mfma_f32_16x16x32_f16(al, bh, acc[t], 0, 0, 0);
    }
    __syncthreads();
  }
  // epilogue: C[row][col], col = lane&15, row = (lane>>4)*4 + i
  int rbase = bm + wv*16 + (lane >> 4)*4;
  int cl = lane & 15;
  int NR = N - xlCols;
  #pragma unroll
  for (int t = 0; t < 8; t++){
    int col = bn + t*16 + cl;
    float bv = bias[col];
    bool isXl = (bn + t*16) < xlCols;   // block-uniform per tile
    #pragma unroll
    for (int i = 0; i < 4; i++){
      int r = rbase + i;
      if (r < M){
        float o = acc[t][i] + bv;
        if (isXl) Cxl[(size_t)r*xlCols + col] = (_Float16)o;
        else      Cxr[(size_t)r*NR + (col - xlCols)] = o;
      }
    }
  }
}

// ---------------- DPP adds (VALU pipe, no DS ops) ----------------

template<int CTRL>
__device__ __forceinline__ float dpp_add(float x){
  int t = __builtin_amdgcn_update_dpp(0, __float_as_int(x), CTRL, 0xf, 0xf, true);
  return x + __int_as_float(t);
}

// ---------------- fused GATv2 layer: 16-lane groups, fp16 gather ----------
// r9: exact r7 structure restored (r8's 8-lane/h8 variant starved MLP at
// avg degree 17: only 4 gathers in flight -> occupancy 34%, regressed).
// One wave per node; 4 groups of 16 lanes; h4 (8B) gather loads; 2 edges/
// iter (H=2), batched 8-deep. Workgroup = 128 (2 waves) so a finished
// node's wave frees its slot sooner (was 4 waves/WG -> drain imbalance).

template<int H>
__global__ __launch_bounds__(128) void k_gat_fused(
    const _Float16* __restrict__ xlh, const float* __restrict__ xr,
    const int* __restrict__ rowptr, const int* __restrict__ srcs,
    const float* __restrict__ att, const float* __restrict__ bias,
    float* __restrict__ out, int n){
  int gid = blockIdx.x * blockDim.x + threadIdx.x;
  int nd = gid >> 6, lane = gid & 63;
  if (nd >= n) return;
  constexpr int SHIFTB = (H == 2) ? 8 : 7;      // bytes per fp16 xl row
  constexpr int EPI = (H == 2) ? 2 : 4;         // edges per iteration
  const int q = lane & 15;
  const int hsel = (H == 2) ? ((lane >> 4) & 1) : 0;
  const int elane = (H == 2) ? (lane >> 5) : (lane >> 4);  // edge-in-iter
  const int fpos = hsel*64 + q*4;               // float offset of lane's quad
  const unsigned foff = (unsigned)fpos * 2u;    // byte offset (fp16)
  const char* __restrict__ xbase = (const char*)xlh;
  v4f xrv = *(const v4f*)(xr + (size_t)nd*(H*64) + fpos);
  v4f av  = *(const v4f*)(att + fpos);
  v4f acc = {0.f, 0.f, 0.f, 0.f};
  float den = 0.f;
  int s0 = rowptr[nd], s1 = rowptr[nd+1];
  for (int base = s0; base < s1; base += 64){
    int idx = base + lane;
    int sv = (idx < s1) ? srcs[idx] : 0;   // pad lanes hold 0 (valid row)
    int cnt = min(64, s1 - base);
    // batched gather: U iterations, all loads issued before any compute
    auto batchU = [&](int i, auto Uc, bool full){
      constexpr int U = decltype(Uc)::value;
      int aidx[U];
      h4 hv[U];
      #pragma unroll
      for (int u = 0; u < U; u++)
        aidx[u] = __builtin_amdgcn_ds_bpermute((i + u*EPI + elane) << 2, sv);
      #pragma unroll
      for (int u = 0; u < U; u++)
        hv[u] = *(const h4*)(xbase + (((unsigned)aidx[u] << SHIFTB) + foff));
      #pragma unroll
      for (int u = 0; u < U; u++){
        v4f xv = {(float)hv[u].x, (float)hv[u].y, (float)hv[u].z, (float)hv[u].w};
        v4f t  = xv + xrv;
        v4f lt = __builtin_elementwise_max(t, t * 0.2f);   // leaky_relu 0.2
        v4f pr = lt * av;
        float p = (pr.x + pr.y) + (pr.z + pr.w);
        p = dpp_add<0x111>(p);   // row_shr:1
        p = dpp_add<0x112>(p);   // row_shr:2
        p = dpp_add<0x114>(p);   // row_shr:4
        p = dpp_add<0x118>(p);   // row_shr:8 -> lane15 of each 16-row = sum
        p = __int_as_float(__builtin_amdgcn_ds_swizzle(__float_as_int(p), 0x1F0));
        float ex = __expf(p);    // scores bounded; softmax w/o max
        if (!full) ex = (elane < cnt - (i + u*EPI)) ? ex : 0.f;  // tail mask
        den += ex;
        acc += xv * ex;
      }
    };
    int i = 0;
    for (; i + 8*EPI <= cnt; i += 8*EPI) batchU(i, IC<8>{}, true);
    if (i + 4*EPI <= cnt){ batchU(i, IC<4>{}, true); i += 4*EPI; }
    if (i + 2*EPI <= cnt){ batchU(i, IC<2>{}, true); i += 2*EPI; }
    for (; i < cnt; i += EPI) batchU(i, IC<1>{}, i + EPI <= cnt);
  }
  // combine groups that accumulated different edges (same output slot)
  if (H == 1){
    den   += __shfl_xor(den,   16, 64);
    acc.x += __shfl_xor(acc.x, 16, 64);
    acc.y += __shfl_xor(acc.y, 16, 64);
    acc.z += __shfl_xor(acc.z, 16, 64);
    acc.w += __shfl_xor(acc.w, 16, 64);
  }
  den   += __shfl_xor(den,   32, 64);
  acc.x += __shfl_xor(acc.x, 32, 64);
  acc.y += __shfl_xor(acc.y, 32, 64);
  acc.z += __shfl_xor(acc.z, 32, 64);
  acc.w += __shfl_xor(acc.w, 32, 64);
  if (lane < 16*H){
    v4f bv = *(const v4f*)(bias + fpos);
    float inv = 1.f / (den + 1e-16f);
    v4f o = acc * inv + bv;
    v4f z = {0.f, 0.f, 0.f, 0.f};
    o = __builtin_elementwise_max(o, z);
    *(v4f*)(out + (size_t)nd*(H*64) + fpos) = o;
  }
}

// ---------------- gate: relu(h2@gw1+gb1)@gw2+gb2 -> exp, fused ------------

__global__ __launch_bounds__(256) void k_gate(
    const float* __restrict__ h2, const float* __restrict__ gw1,
    const float* __restrict__ gb1, const float* __restrict__ gw2,
    const float* __restrict__ gb2, float* __restrict__ exn, int M){
  __shared__ float As[32][64 + 4];
  __shared__ float Ws[32][64];
  int bm = blockIdx.x * 64;
  int tid = threadIdx.x;
  int tx = tid & 15, ty = tid >> 4;
  float acc[4][4] = {};
  for (int k0 = 0; k0 < 64; k0 += 32){
    #pragma unroll
    for (int l = 0; l < 2; l++){
      int idx = tid + l*256;
      int r = idx >> 3, c4 = (idx & 7) * 4;
      float4 v = make_float4(0.f, 0.f, 0.f, 0.f);
      if (bm + r < M) v = *(const float4*)(h2 + (size_t)(bm + r)*64 + k0 + c4);
      As[c4+0][r] = v.x; As[c4+1][r] = v.y; As[c4+2][r] = v.z; As[c4+3][r] = v.w;
      int kr = idx >> 4, wc4 = (idx & 15) * 4;
      *(float4*)(&Ws[kr][wc4]) = *(const float4*)(gw1 + (size_t)(k0 + kr)*64 + wc4);
    }
    __syncthreads();
    #pragma unroll
    for (int k = 0; k < 32; k++){
      float4 a4 = *(const float4*)(&As[k][ty*4]);
      float4 w4 = *(const float4*)(&Ws[k][tx*4]);
      float av[4] = {a4.x, a4.y, a4.z, a4.w};
      float wv[4] = {w4.x, w4.y, w4.z, w4.w};
      #pragma unroll
      for (int i = 0; i < 4; i++)
        #pragma unroll
        for (int j = 0; j < 4; j++)
          acc[i][j] = fmaf(av[i], wv[j], acc[i][j]);
    }
    __syncthreads();
  }
  float4 b4 = *(const float4*)(gb1 + tx*4);
  float4 w2 = *(const float4*)(gw2 + tx*4);
  float gb2v = gb2[0];
  #pragma unroll
  for (int i = 0; i < 4; i++){
    float p = fmaxf(acc[i][0] + b4.x, 0.f) * w2.x;
    p = fmaf(fmaxf(acc[i][1] + b4.y, 0.f), w2.y, p);
    p = fmaf(fmaxf(acc[i][2] + b4.z, 0.f), w2.z, p);
    p = fmaf(fmaxf(acc[i][3] + b4.w, 0.f), w2.w, p);
    p = dpp_add<0x111>(p);
    p = dpp_add<0x112>(p);
    p = dpp_add<0x114>(p);
    p = dpp_add<0x118>(p);     // lane tx==15 holds the 16-lane row sum
    if (tx == 15){
      int r = bm + ty*4 + i;
      if (r < M) exn[r] = __expf(p + gb2v);
    }
  }
}

// ---------------- pool + MLP head: one block per batch segment ----------------

__global__ __launch_bounds__(1024) void k_pool_mlp(
    const float* __restrict__ h2, const float* __restrict__ exn,
    const int* __restrict__ batch, int n,
    const float* __restrict__ l1w, const float* __restrict__ l1b,
    const float* __restrict__ l2w, const float* __restrict__ l2b,
    float* __restrict__ out){
  __shared__ float accs[16][64];
  __shared__ float dens[16];
  int b = blockIdx.x;
  int tid = threadIdx.x, lane = tid & 63, wv = tid >> 6;
  int lo = 0, hi = n;
  while (lo < hi){ int m = (lo + hi) >> 1; if (batch[m] < b) lo = m + 1; else hi = m; }
  int start = lo;
  hi = n;
  while (lo < hi){ int m = (lo + hi) >> 1; if (batch[m] < b + 1) lo = m + 1; else hi = m; }
  int end = lo;
  float acc = 0.f, den = 0.f;
  for (int nd = start + wv; nd < end; nd += 16){
    float ex = exn[nd];
    den += ex;
    acc = fmaf(ex, h2[(size_t)nd*64 + lane], acc);
  }
  accs[wv][lane] = acc;
  if (lane == 0) dens[wv] = den;
  __syncthreads();
  if (wv == 0){
    float p = 0.f, d = 0.f;
    #pragma unroll
    for (int w = 0; w < 16; w++){ p += accs[w][lane]; d += dens[w]; }
    p = p / (d + 1e-16f);
    float t = l1b[lane];
    #pragma unroll
    for (int k = 0; k < 64; k++)
      t = fmaf(__shfl(p, k, 64), l1w[k*64 + lane], t);
    t = fmaxf(t, 0.f) * l2w[lane];
    #pragma unroll
    for (int off = 32; off; off >>= 1) t += __shfl_xor(t, off, 64);
    if (lane == 0) out[b] = t + l2b[0];
  }
}

// ---------------- launch (12 dispatches) ----------------

extern "C" void kernel_launch(void* const* d_in, const int* in_sizes, int n_in,
                              void* d_out, int out_size, void* d_ws, size_t ws_size,
                              hipStream_t stream){
  const float* x    = (const float*)d_in[0];
  const int*   ei   = (const int*)  d_in[1];
  const int*   batch= (const int*)  d_in[2];
  const float* w1_l = (const float*)d_in[3];  const float* b1_l = (const float*)d_in[4];
  const float* w1_r = (const float*)d_in[5];  const float* b1_r = (const float*)d_in[6];
  const float* att1 = (const float*)d_in[7];  const float* bias1= (const float*)d_in[8];
  const float* w2_l = (const float*)d_in[9];  const float* b2_l = (const float*)d_in[10];
  const float* w2_r = (const float*)d_in[11]; const float* b2_r = (const float*)d_in[12];
  const float* att2 = (const float*)d_in[13]; const float* bias2= (const float*)d_in[14];
  const float* gw1  = (const float*)d_in[15]; const float* gb1  = (const float*)d_in[16];
  const float* gw2  = (const float*)d_in[17]; const float* gb2  = (const float*)d_in[18];
  const float* l1w  = (const float*)d_in[19]; const float* l1b  = (const float*)d_in[20];
  const float* l2w  = (const float*)d_in[21]; const float* l2b  = (const float*)d_in[22];

  const int n = in_sizes[0] / 128;
  const int E = in_sizes[1] / 2;
  const int Bb = out_size;
  const int Etot = E + n;
  const int* srcp = ei;
  const int* dstp = ei + E;

  char* wsbase = (char*)d_ws;
  size_t off = 0;
  auto alloc = [&](size_t bytes)->char*{
    char* p = wsbase + off;
    off = (off + bytes + 255) & ~(size_t)255;
    return p;
  };
  int*   deg    = (int*)  alloc((size_t)n*4);
  int*   rowptr = (int*)  alloc((size_t)(n+1)*4);
  int*   cursor = (int*)  alloc((size_t)n*4);
  int*   bsum   = (int*)  alloc(1024);
  int*   srcs   = (int*)  alloc((size_t)Etot*4);
  _Float16* wc1h = (_Float16*)alloc(256*128*2);
  _Float16* wc1l = (_Float16*)alloc(256*128*2);
  _Float16* wc2h = (_Float16*)alloc(128*128*2);
  _Float16* wc2l = (_Float16*)alloc(128*128*2);
  float* bc1    = (float*)alloc(256*4);
  float* bc2    = (float*)alloc(128*4);
  // region A: xlh1 [n][128] fp16; reused as xlh2 [n][64] fp16
  _Float16* xlh1 = (_Float16*)alloc((size_t)n*128*2);
  // region B: xr1 [n][128] fp32; reused as xr2 [n][64] + h2 [n][64]
  float* xr1    = (float*)alloc((size_t)n*128*4);
  // region C: h1 [n][128] fp32; reused as exn [n]
  float* h1     = (float*)alloc((size_t)n*128*4);
  _Float16* xlh2 = xlh1;
  float* xr2 = xr1;
  float* h2  = xr1 + (size_t)n*64;
  float* exn = h1;

  int nb = (n + 255) / 256;
  int ib = (((n > 32768) ? n : 32768) + 255) / 256;

  // CSR build + weight packing
  k_init<<<ib, 256, 0, stream>>>(w1_l, w1_r, b1_l, b1_r, w2_l, w2_r, b2_l, b2_r,
                                 wc1h, wc1l, wc2h, wc2l, bc1, bc2, deg, n);
  k_hist_xcd<<<8*SCB, 256, 0, stream>>>(dstp, deg, E, n);
  k_scan1<<<nb, 256, 0, stream>>>(deg, rowptr, bsum, n);
  k_scan2<<<1, 256, 0, stream>>>(bsum, nb);
  k_scan3<<<nb, 256, 0, stream>>>(rowptr, bsum, srcs, cursor, n, Etot);
  k_scatter_xcd<<<8*SCB, 256, 0, stream>>>(srcp, dstp, cursor, srcs, E, n);

  // layer 1: mfma gemm -> xlh1 (fp16, cols 0..127) + xr1 (fp32, cols 128..255)
  dim3 g1((n + MBM - 1)/MBM, 2);
  k_gemm_mfma<<<g1, 256, 0, stream>>>(x, wc1h, wc1l, bc1, xlh1, xr1, n, 128, 256, 128);
  long long thr = (long long)n * 64;           // one wave per node
  int gatb = (int)((thr + 127)/128);           // 2 waves per workgroup
  k_gat_fused<2><<<gatb, 128, 0, stream>>>(xlh1, xr1, rowptr, srcs, att1, bias1, h1, n);

  // layer 2: mfma gemm -> xlh2 (fp16, cols 0..63) + xr2 (fp32, cols 64..127)
  dim3 g2((n + MBM - 1)/MBM, 1);
  k_gemm_mfma<<<g2, 256, 0, stream>>>(h1, wc2h, wc2l, bc2, xlh2, xr2, n, 128, 128, 64);
  k_gat_fused<1><<<gatb, 128, 0, stream>>>(xlh2, xr2, rowptr, srcs, att2, bias2, h2, n);

  // gate (gemm + gw2-dot + exp fused)
  k_gate<<<(n + 63)/64, 256, 0, stream>>>(h2, gw1, gb1, gw2, gb2, exn, n);

  // pool + MLP head
  k_pool_mlp<<<Bb, 1024, 0, stream>>>(h2, exn, batch, n, l1w, l1b, l2w, l2b, (float*)d_out);
}

// Round 11
// 326.410 us; speedup vs baseline: 1.1207x; 1.0315x over previous
//
#include <hip/hip_runtime.h>

typedef float v2f __attribute__((ext_vector_type(2)));
typedef float v4f __attribute__((ext_vector_type(4)));
typedef _Float16 h4 __attribute__((ext_vector_type(4)));
typedef _Float16 f16x8 __attribute__((ext_vector_type(8)));

template<int N> struct IC { static constexpr int value = N; };

#define SCB 256   // chunks per XCD region
#define MBM 64
#define MBN 128
#define MBK 32

// ---------------- fused init(weight pack) + XCD hist ----------------
// r11: deg zeroing moved to hipMemsetAsync; weight packing (128 blocks)
// and the XCD-partitioned histogram (2048 blocks) are independent ->
// one heterogeneous co-launch. Saves one dispatch + overlaps the two.

__global__ __launch_bounds__(256) void k_init_hist(
    const float* __restrict__ w1_l, const float* __restrict__ w1_r,
    const float* __restrict__ b1_l, const float* __restrict__ b1_r,
    const float* __restrict__ w2_l, const float* __restrict__ w2_r,
    const float* __restrict__ b2_l, const float* __restrict__ b2_r,
    _Float16* __restrict__ wc1h, _Float16* __restrict__ wc1l,
    _Float16* __restrict__ wc2h, _Float16* __restrict__ wc2l,
    float* __restrict__ bc1, float* __restrict__ bc2,
    const int* __restrict__ dstp, int* __restrict__ deg, int E, int n){
  int b = blockIdx.x;
  if (b < 128){
    int i = b*256 + threadIdx.x;      // 0..32767
    {                                  // wc1t: [col 0..255][k 0..127]
      int col = i >> 7, k = i & 127;
      float v = (col < 128) ? w1_l[k*128 + col] : w1_r[k*128 + (col - 128)];
      _Float16 h = (_Float16)v;
      wc1h[i] = h; wc1l[i] = (_Float16)(v - (float)h);
    }
    if (i < 128*128){                  // wc2t: [col 0..127][k 0..127]
      int col = i >> 7, k = i & 127;
      float v = (col < 64) ? w2_l[k*64 + col] : w2_r[k*64 + (col - 64)];
      _Float16 h = (_Float16)v;
      wc2h[i] = h; wc2l[i] = (_Float16)(v - (float)h);
    }
    if (i < 256) bc1[i] = (i < 128) ? b1_l[i] : b1_r[i - 128];
    if (i < 128) bc2[i] = (i < 64)  ? b2_l[i] : b2_r[i - 64];
  } else {
    int hb = b - 128;
    int reg = hb & 7;
    int chunk = hb >> 3;
    int lo = (int)((long long)reg * n >> 3);
    int hi = (int)((long long)(reg + 1) * n >> 3);
    int per = (E + SCB - 1) / SCB;
    int e0 = chunk * per;
    int e1 = min(E, e0 + per);
    for (int e = e0 + threadIdx.x; e < e1; e += 256){
      int d = dstp[e];
      if (d >= lo && d < hi) atomicAdd(&deg[d], 1);
    }
  }
}

__global__ void k_scan1(const int* __restrict__ deg, int* __restrict__ rowptr,
                        int* __restrict__ bsum, int n){
  __shared__ int s[256];
  int i = blockIdx.x*256 + threadIdx.x;
  int v = (i < n) ? deg[i] + 1 : 0;   // +1 = self loop
  s[threadIdx.x] = v;
  __syncthreads();
  for (int off = 1; off < 256; off <<= 1){
    int t = (threadIdx.x >= off) ? s[threadIdx.x - off] : 0;
    __syncthreads();
    s[threadIdx.x] += t;
    __syncthreads();
  }
  if (i < n) rowptr[i] = s[threadIdx.x] - v;   // exclusive within block
  if (threadIdx.x == 255) bsum[blockIdx.x] = s[255];
}

__global__ void k_scan2(int* bsum, int nb){
  __shared__ int s[256];
  int v = (threadIdx.x < nb) ? bsum[threadIdx.x] : 0;
  s[threadIdx.x] = v;
  __syncthreads();
  for (int off = 1; off < 256; off <<= 1){
    int t = (threadIdx.x >= off) ? s[threadIdx.x - off] : 0;
    __syncthreads();
    s[threadIdx.x] += t;
    __syncthreads();
  }
  if (threadIdx.x < nb) bsum[threadIdx.x] = s[threadIdx.x] - v;  // exclusive
}

// scan3 + scatter_init fused: finalize rowptr, seed self-loop + cursor
__global__ void k_scan3(int* rowptr, const int* __restrict__ bsum,
                        int* __restrict__ srcs, int* __restrict__ cursor,
                        int n, int total){
  int i = blockIdx.x*256 + threadIdx.x;
  if (i < n){
    int b = rowptr[i] + bsum[blockIdx.x];
    rowptr[i] = b;
    srcs[b] = i;          // self loop at segment head
    cursor[i] = b + 1;
  }
  if (i == 0) rowptr[n] = total;
}

// ---------------- split-fp16 MFMA GEMM body (shared) ----------------
// MFMA 16x16x32_f16 fragments are 8 contiguous K per lane; C: col=lane&15,
// row=(lane>>4)*4+i. Split precision: D = Ah·Wh + Ah·Wl + Al·Wh.

__device__ __forceinline__ int lds_idx(int row, int k){
  return row*32 + ((((k >> 3) ^ row) & 3) << 3) + (k & 7);
}

__device__ __forceinline__ void gemm_mfma_body(
    const float* __restrict__ A, const _Float16* __restrict__ Wh,
    const _Float16* __restrict__ Wl, const float* __restrict__ bias,
    _Float16* __restrict__ Cxl, float* __restrict__ Cxr,
    int M, int K, int N, int xlCols, int bm, int bn){
  __shared__ _Float16 Ah[MBM*MBK], Al[MBM*MBK];
  __shared__ _Float16 Bh[MBN*MBK], Bl[MBN*MBK];
  int tid = threadIdx.x;
  int lane = tid & 63, wv = tid >> 6;
  v4f acc[8] = {};
  const int fragoff = (lane & 15)*32 + ((((lane >> 4) ^ lane) & 3) << 3);
  for (int k0 = 0; k0 < K; k0 += MBK){
    #pragma unroll
    for (int l = 0; l < 2; l++){
      int idx = tid + l*256;
      int r = idx >> 3, kq = (idx & 7) * 4;
      float4 v = make_float4(0.f, 0.f, 0.f, 0.f);
      if (bm + r < M) v = *(const float4*)(A + (size_t)(bm + r)*K + k0 + kq);
      _Float16 e0 = (_Float16)v.x, e1 = (_Float16)v.y,
               e2 = (_Float16)v.z, e3 = (_Float16)v.w;
      h4 hh = {e0, e1, e2, e3};
      h4 ll = {(_Float16)(v.x - (float)e0), (_Float16)(v.y - (float)e1),
               (_Float16)(v.z - (float)e2), (_Float16)(v.w - (float)e3)};
      int o = lds_idx(r, kq);
      *(h4*)(&Ah[o]) = hh;
      *(h4*)(&Al[o]) = ll;
    }
    #pragma unroll
    for (int l = 0; l < 2; l++){
      int idx = tid + l*256;
      int c = idx >> 2, kc = (idx & 3) * 8;
      size_t go = (size_t)(bn + c)*K + k0 + kc;
      int o = lds_idx(c, kc);
      *(f16x8*)(&Bh[o]) = *(const f16x8*)(Wh + go);
      *(f16x8*)(&Bl[o]) = *(const f16x8*)(Wl + go);
    }
    __syncthreads();
    f16x8 ah = *(const f16x8*)(&Ah[wv*16*32 + fragoff]);
    f16x8 al = *(const f16x8*)(&Al[wv*16*32 + fragoff]);
    #pragma unroll
    for (int t = 0; t < 8; t++){
      f16x8 bh = *(const f16x8*)(&Bh[t*16*32 + fragoff]);
      f16x8 bl = *(const f16x8*)(&Bl[t*16*32 + fragoff]);
      acc[t] = __builtin_amdgcn_mfma_f32_16x16x32_f16(ah, bh, acc[t], 0, 0, 0);
      acc[t] = __builtin_amdgcn_mfma_f32_16x16x32_f16(ah, bl, acc[t], 0, 0, 0);
      acc[t] = __builtin_amdgcn_mfma_f32_16x16x32_f16(al, bh, acc[t], 0, 0, 0);
    }
    __syncthreads();
  }
  int rbase = bm + wv*16 + (lane >> 4)*4;
  int cl = lane & 15;
  int NR = N - xlCols;
  #pragma unroll
  for (int t = 0; t < 8; t++){
    int col = bn + t*16 + cl;
    float bv = bias[col];
    bool isXl = (bn + t*16) < xlCols;   // block-uniform per tile
    #pragma unroll
    for (int i = 0; i < 4; i++){
      int r = rbase + i;
      if (r < M){
        float o = acc[t][i] + bv;
        if (isXl) Cxl[(size_t)r*xlCols + col] = (_Float16)o;
        else      Cxr[(size_t)r*NR + (col - xlCols)] = o;
      }
    }
  }
}

// standalone GEMM (layer 2)
__global__ __launch_bounds__(256) void k_gemm_mfma(
    const float* __restrict__ A, const _Float16* __restrict__ Wh,
    const _Float16* __restrict__ Wl, const float* __restrict__ bias,
    _Float16* __restrict__ Cxl, float* __restrict__ Cxr,
    int M, int K, int N, int xlCols){
  gemm_mfma_body(A, Wh, Wl, bias, Cxl, Cxr, M, K, N, xlCols,
                 blockIdx.x * MBM, blockIdx.y * MBN);
}

// ---------------- fused XCD scatter + layer-1 GEMM ----------------
// r11: scatter (needs scan3) and gemm1 (needs only weights+x) are
// independent -> co-launch. Blocks [0,2048) scatter, rest gemm (flattened
// 782x2 grid). Disjoint writes; both complete at kernel end, before gat1.

__global__ __launch_bounds__(256) void k_scatter_gemm(
    const int* __restrict__ srcp, const int* __restrict__ dstp,
    int* __restrict__ cursor, int* __restrict__ srcs, int E, int n,
    const float* __restrict__ A, const _Float16* __restrict__ Wh,
    const _Float16* __restrict__ Wl, const float* __restrict__ bias,
    _Float16* __restrict__ Cxl, float* __restrict__ Cxr,
    int M, int K, int N, int xlCols, int nbx){
  int b = blockIdx.x;
  if (b < 8*SCB){
    int reg = b & 7;
    int chunk = b >> 3;
    int lo = (int)((long long)reg * n >> 3);
    int hi = (int)((long long)(reg + 1) * n >> 3);
    int per = (E + SCB - 1) / SCB;
    int e0 = chunk * per;
    int e1 = min(E, e0 + per);
    for (int e = e0 + threadIdx.x; e < e1; e += 256){
      int d = dstp[e];
      if (d >= lo && d < hi){
        int p = atomicAdd(&cursor[d], 1);
        srcs[p] = srcp[e];
      }
    }
  } else {
    int g = b - 8*SCB;
    int bx = g % nbx, by = g / nbx;
    gemm_mfma_body(A, Wh, Wl, bias, Cxl, Cxr, M, K, N, xlCols,
                   bx * MBM, by * MBN);
  }
}

// ---------------- DPP adds (VALU pipe, no DS ops) ----------------

template<int CTRL>
__device__ __forceinline__ float dpp_add(float x){
  int t = __builtin_amdgcn_update_dpp(0, __float_as_int(x), CTRL, 0xf, 0xf, true);
  return x + __int_as_float(t);
}

// ---------------- fused GATv2 layer: 16-lane groups, fp16 gather ----------
// r7-proven structure: one wave per node; 4 groups of 16 lanes; h4 (8B)
// gather loads; 2 edges/iter (H=2) batched 8-deep. WG=128 (2 waves).

template<int H>
__global__ __launch_bounds__(128) void k_gat_fused(
    const _Float16* __restrict__ xlh, const float* __restrict__ xr,
    const int* __restrict__ rowptr, const int* __restrict__ srcs,
    const float* __restrict__ att, const float* __restrict__ bias,
    float* __restrict__ out, int n){
  int gid = blockIdx.x * blockDim.x + threadIdx.x;
  int nd = gid >> 6, lane = gid & 63;
  if (nd >= n) return;
  constexpr int SHIFTB = (H == 2) ? 8 : 7;      // bytes per fp16 xl row
  constexpr int EPI = (H == 2) ? 2 : 4;         // edges per iteration
  const int q = lane & 15;
  const int hsel = (H == 2) ? ((lane >> 4) & 1) : 0;
  const int elane = (H == 2) ? (lane >> 5) : (lane >> 4);  // edge-in-iter
  const int fpos = hsel*64 + q*4;               // float offset of lane's quad
  const unsigned foff = (unsigned)fpos * 2u;    // byte offset (fp16)
  const char* __restrict__ xbase = (const char*)xlh;
  v4f xrv = *(const v4f*)(xr + (size_t)nd*(H*64) + fpos);
  v4f av  = *(const v4f*)(att + fpos);
  v4f acc = {0.f, 0.f, 0.f, 0.f};
  float den = 0.f;
  int s0 = rowptr[nd], s1 = rowptr[nd+1];
  for (int base = s0; base < s1; base += 64){
    int idx = base + lane;
    int sv = (idx < s1) ? srcs[idx] : 0;   // pad lanes hold 0 (valid row)
    int cnt = min(64, s1 - base);
    // batched gather: U iterations, all loads issued before any compute
    auto batchU = [&](int i, auto Uc, bool full){
      constexpr int U = decltype(Uc)::value;
      int aidx[U];
      h4 hv[U];
      #pragma unroll
      for (int u = 0; u < U; u++)
        aidx[u] = __builtin_amdgcn_ds_bpermute((i + u*EPI + elane) << 2, sv);
      #pragma unroll
      for (int u = 0; u < U; u++)
        hv[u] = *(const h4*)(xbase + (((unsigned)aidx[u] << SHIFTB) + foff));
      #pragma unroll
      for (int u = 0; u < U; u++){
        v4f xv = {(float)hv[u].x, (float)hv[u].y, (float)hv[u].z, (float)hv[u].w};
        v4f t  = xv + xrv;
        v4f lt = __builtin_elementwise_max(t, t * 0.2f);   // leaky_relu 0.2
        v4f pr = lt * av;
        float p = (pr.x + pr.y) + (pr.z + pr.w);
        p = dpp_add<0x111>(p);   // row_shr:1
        p = dpp_add<0x112>(p);   // row_shr:2
        p = dpp_add<0x114>(p);   // row_shr:4
        p = dpp_add<0x118>(p);   // row_shr:8 -> lane15 of each 16-row = sum
        p = __int_as_float(__builtin_amdgcn_ds_swizzle(__float_as_int(p), 0x1F0));
        float ex = __expf(p);    // scores bounded; softmax w/o max
        if (!full) ex = (elane < cnt - (i + u*EPI)) ? ex : 0.f;  // tail mask
        den += ex;
        acc += xv * ex;
      }
    };
    int i = 0;
    for (; i + 8*EPI <= cnt; i += 8*EPI) batchU(i, IC<8>{}, true);
    if (i + 4*EPI <= cnt){ batchU(i, IC<4>{}, true); i += 4*EPI; }
    if (i + 2*EPI <= cnt){ batchU(i, IC<2>{}, true); i += 2*EPI; }
    for (; i < cnt; i += EPI) batchU(i, IC<1>{}, i + EPI <= cnt);
  }
  // combine groups that accumulated different edges (same output slot)
  if (H == 1){
    den   += __shfl_xor(den,   16, 64);
    acc.x += __shfl_xor(acc.x, 16, 64);
    acc.y += __shfl_xor(acc.y, 16, 64);
    acc.z += __shfl_xor(acc.z, 16, 64);
    acc.w += __shfl_xor(acc.w, 16, 64);
  }
  den   += __shfl_xor(den,   32, 64);
  acc.x += __shfl_xor(acc.x, 32, 64);
  acc.y += __shfl_xor(acc.y, 32, 64);
  acc.z += __shfl_xor(acc.z, 32, 64);
  acc.w += __shfl_xor(acc.w, 32, 64);
  if (lane < 16*H){
    v4f bv = *(const v4f*)(bias + fpos);
    float inv = 1.f / (den + 1e-16f);
    v4f o = acc * inv + bv;
    v4f z = {0.f, 0.f, 0.f, 0.f};
    o = __builtin_elementwise_max(o, z);
    *(v4f*)(out + (size_t)nd*(H*64) + fpos) = o;
  }
}

// ---------------- gate: relu(h2@gw1+gb1)@gw2+gb2 -> exp, fused ------------

__global__ __launch_bounds__(256) void k_gate(
    const float* __restrict__ h2, const float* __restrict__ gw1,
    const float* __restrict__ gb1, const float* __restrict__ gw2,
    const float* __restrict__ gb2, float* __restrict__ exn, int M){
  __shared__ float As[32][64 + 4];
  __shared__ float Ws[32][64];
  int bm = blockIdx.x * 64;
  int tid = threadIdx.x;
  int tx = tid & 15, ty = tid >> 4;
  float acc[4][4] = {};
  for (int k0 = 0; k0 < 64; k0 += 32){
    #pragma unroll
    for (int l = 0; l < 2; l++){
      int idx = tid + l*256;
      int r = idx >> 3, c4 = (idx & 7) * 4;
      float4 v = make_float4(0.f, 0.f, 0.f, 0.f);
      if (bm + r < M) v = *(const float4*)(h2 + (size_t)(bm + r)*64 + k0 + c4);
      As[c4+0][r] = v.x; As[c4+1][r] = v.y; As[c4+2][r] = v.z; As[c4+3][r] = v.w;
      int kr = idx >> 4, wc4 = (idx & 15) * 4;
      *(float4*)(&Ws[kr][wc4]) = *(const float4*)(gw1 + (size_t)(k0 + kr)*64 + wc4);
    }
    __syncthreads();
    #pragma unroll
    for (int k = 0; k < 32; k++){
      float4 a4 = *(const float4*)(&As[k][ty*4]);
      float4 w4 = *(const float4*)(&Ws[k][tx*4]);
      float av[4] = {a4.x, a4.y, a4.z, a4.w};
      float wv[4] = {w4.x, w4.y, w4.z, w4.w};
      #pragma unroll
      for (int i = 0; i < 4; i++)
        #pragma unroll
        for (int j = 0; j < 4; j++)
          acc[i][j] = fmaf(av[i], wv[j], acc[i][j]);
    }
    __syncthreads();
  }
  float4 b4 = *(const float4*)(gb1 + tx*4);
  float4 w2 = *(const float4*)(gw2 + tx*4);
  float gb2v = gb2[0];
  #pragma unroll
  for (int i = 0; i < 4; i++){
    float p = fmaxf(acc[i][0] + b4.x, 0.f) * w2.x;
    p = fmaf(fmaxf(acc[i][1] + b4.y, 0.f), w2.y, p);
    p = fmaf(fmaxf(acc[i][2] + b4.z, 0.f), w2.z, p);
    p = fmaf(fmaxf(acc[i][3] + b4.w, 0.f), w2.w, p);
    p = dpp_add<0x111>(p);
    p = dpp_add<0x112>(p);
    p = dpp_add<0x114>(p);
    p = dpp_add<0x118>(p);     // lane tx==15 holds the 16-lane row sum
    if (tx == 15){
      int r = bm + ty*4 + i;
      if (r < M) exn[r] = __expf(p + gb2v);
    }
  }
}

// ---------------- pool + MLP head: one block per batch segment ----------------

__global__ __launch_bounds__(1024) void k_pool_mlp(
    const float* __restrict__ h2, const float* __restrict__ exn,
    const int* __restrict__ batch, int n,
    const float* __restrict__ l1w, const float* __restrict__ l1b,
    const float* __restrict__ l2w, const float* __restrict__ l2b,
    float* __restrict__ out){
  __shared__ float accs[16][64];
  __shared__ float dens[16];
  int b = blockIdx.x;
  int tid = threadIdx.x, lane = tid & 63, wv = tid >> 6;
  int lo = 0, hi = n;
  while (lo < hi){ int m = (lo + hi) >> 1; if (batch[m] < b) lo = m + 1; else hi = m; }
  int start = lo;
  hi = n;
  while (lo < hi){ int m = (lo + hi) >> 1; if (batch[m] < b + 1) lo = m + 1; else hi = m; }
  int end = lo;
  float acc = 0.f, den = 0.f;
  for (int nd = start + wv; nd < end; nd += 16){
    float ex = exn[nd];
    den += ex;
    acc = fmaf(ex, h2[(size_t)nd*64 + lane], acc);
  }
  accs[wv][lane] = acc;
  if (lane == 0) dens[wv] = den;
  __syncthreads();
  if (wv == 0){
    float p = 0.f, d = 0.f;
    #pragma unroll
    for (int w = 0; w < 16; w++){ p += accs[w][lane]; d += dens[w]; }
    p = p / (d + 1e-16f);
    float t = l1b[lane];
    #pragma unroll
    for (int k = 0; k < 64; k++)
      t = fmaf(__shfl(p, k, 64), l1w[k*64 + lane], t);
    t = fmaxf(t, 0.f) * l2w[lane];
    #pragma unroll
    for (int off = 32; off; off >>= 1) t += __shfl_xor(t, off, 64);
    if (lane == 0) out[b] = t + l2b[0];
  }
}

// ---------------- launch (10 dispatches + 1 memset) ----------------

extern "C" void kernel_launch(void* const* d_in, const int* in_sizes, int n_in,
                              void* d_out, int out_size, void* d_ws, size_t ws_size,
                              hipStream_t stream){
  const float* x    = (const float*)d_in[0];
  const int*   ei   = (const int*)  d_in[1];
  const int*   batch= (const int*)  d_in[2];
  const float* w1_l = (const float*)d_in[3];  const float* b1_l = (const float*)d_in[4];
  const float* w1_r = (const float*)d_in[5];  const float* b1_r = (const float*)d_in[6];
  const float* att1 = (const float*)d_in[7];  const float* bias1= (const float*)d_in[8];
  const float* w2_l = (const float*)d_in[9];  const float* b2_l = (const float*)d_in[10];
  const float* w2_r = (const float*)d_in[11]; const float* b2_r = (const float*)d_in[12];
  const float* att2 = (const float*)d_in[13]; const float* bias2= (const float*)d_in[14];
  const float* gw1  = (const float*)d_in[15]; const float* gb1  = (const float*)d_in[16];
  const float* gw2  = (const float*)d_in[17]; const float* gb2  = (const float*)d_in[18];
  const float* l1w  = (const float*)d_in[19]; const float* l1b  = (const float*)d_in[20];
  const float* l2w  = (const float*)d_in[21]; const float* l2b  = (const float*)d_in[22];

  const int n = in_sizes[0] / 128;
  const int E = in_sizes[1] / 2;
  const int Bb = out_size;
  const int Etot = E + n;
  const int* srcp = ei;
  const int* dstp = ei + E;

  char* wsbase = (char*)d_ws;
  size_t off = 0;
  auto alloc = [&](size_t bytes)->char*{
    char* p = wsbase + off;
    off = (off + bytes + 255) & ~(size_t)255;
    return p;
  };
  int*   deg    = (int*)  alloc((size_t)n*4);
  int*   rowptr = (int*)  alloc((size_t)(n+1)*4);
  int*   cursor = (int*)  alloc((size_t)n*4);
  int*   bsum   = (int*)  alloc(1024);
  int*   srcs   = (int*)  alloc((size_t)Etot*4);
  _Float16* wc1h = (_Float16*)alloc(256*128*2);
  _Float16* wc1l = (_Float16*)alloc(256*128*2);
  _Float16* wc2h = (_Float16*)alloc(128*128*2);
  _Float16* wc2l = (_Float16*)alloc(128*128*2);
  float* bc1    = (float*)alloc(256*4);
  float* bc2    = (float*)alloc(128*4);
  // region A: xlh1 [n][128] fp16; reused as xlh2 [n][64] fp16
  _Float16* xlh1 = (_Float16*)alloc((size_t)n*128*2);
  // region B: xr1 [n][128] fp32; reused as xr2 [n][64] + h2 [n][64]
  float* xr1    = (float*)alloc((size_t)n*128*4);
  // region C: h1 [n][128] fp32; reused as exn [n]
  float* h1     = (float*)alloc((size_t)n*128*4);
  _Float16* xlh2 = xlh1;
  float* xr2 = xr1;
  float* h2  = xr1 + (size_t)n*64;
  float* exn = h1;

  int nb = (n + 255) / 256;
  int nbx = (n + MBM - 1)/MBM;          // 64-row gemm tiles

  // CSR build + weight packing (deg zero via memset; pack+hist co-launched)
  hipMemsetAsync(deg, 0, (size_t)n*4, stream);
  k_init_hist<<<128 + 8*SCB, 256, 0, stream>>>(
      w1_l, w1_r, b1_l, b1_r, w2_l, w2_r, b2_l, b2_r,
      wc1h, wc1l, wc2h, wc2l, bc1, bc2, dstp, deg, E, n);
  k_scan1<<<nb, 256, 0, stream>>>(deg, rowptr, bsum, n);
  k_scan2<<<1, 256, 0, stream>>>(bsum, nb);
  k_scan3<<<nb, 256, 0, stream>>>(rowptr, bsum, srcs, cursor, n, Etot);

  // scatter + layer-1 gemm co-launch (independent; both done before gat1)
  k_scatter_gemm<<<8*SCB + nbx*2, 256, 0, stream>>>(
      srcp, dstp, cursor, srcs, E, n,
      x, wc1h, wc1l, bc1, xlh1, xr1, n, 128, 256, 128, nbx);

  long long thr = (long long)n * 64;           // one wave per node
  int gatb = (int)((thr + 127)/128);           // 2 waves per workgroup
  k_gat_fused<2><<<gatb, 128, 0, stream>>>(xlh1, xr1, rowptr, srcs, att1, bias1, h1, n);

  // layer 2: mfma gemm -> xlh2 (fp16, cols 0..63) + xr2 (fp32, cols 64..127)
  dim3 g2(nbx, 1);
  k_gemm_mfma<<<g2, 256, 0, stream>>>(h1, wc2h, wc2l, bc2, xlh2, xr2, n, 128, 128, 64);
  k_gat_fused<1><<<gatb, 128, 0, stream>>>(xlh2, xr2, rowptr, srcs, att2, bias2, h2, n);

  // gate (gemm + gw2-dot + exp fused)
  k_gate<<<(n + 63)/64, 256, 0, stream>>>(h2, gw1, gb1, gw2, gb2, exn, n);

  // pool + MLP head
  k_pool_mlp<<<Bb, 1024, 0, stream>>>(h2, exn, batch, n, l1w, l1b, l2w, l2b, (float*)d_out);
}